// Round 1
// baseline (2071.313 us; speedup 1.0000x reference)
//
#include <hip/hip_runtime.h>
#include <stdint.h>

// Problem constants
#define NPTS 400000
#define DIM  128
#define KNB  27
#define NSEG 8

typedef _Float16 f16x8 __attribute__((ext_vector_type(8)));
typedef float floatx16 __attribute__((ext_vector_type(16)));

// Workspace layout (bytes). Total ~309 MB + 288 B.
#define OFF_FEATSH 0UL                    // N*128 f16 = 102,400,000
#define OFF_OUT1   102400000UL            // N*128 f16
#define OFF_OUT2   204800000UL            // N*128 f16
#define OFF_PW1    307200000UL            // 27*128*128 f16 = 884,736
#define OFF_PW2    308084736UL
#define OFF_PW3    308969472UL            // 128*128 f16 = 32,768
#define OFF_SEG    309002240UL            // 8*128 f32 = 4096
#define OFF_CNT    309006336UL            // 8 f32 = 32
#define OFF_ZROW   309006368UL            // 256 B zeroed feature row (masked-gather target)
#define ZOFF       309006368              // byte offset of zero row from featsh base

__device__ __forceinline__ void load_lds16(const void* g, void* l) {
  __builtin_amdgcn_global_load_lds(
      (const __attribute__((address_space(1))) void*)g,
      (__attribute__((address_space(3))) void*)l, 16, 0, 0);
}

// ---------------- feats fp32 -> f16 ----------------
__global__ __launch_bounds__(256) void cvt_feats(const float* __restrict__ f,
                                                 _Float16* __restrict__ fh) {
  size_t g = (size_t)blockIdx.x * 256 + threadIdx.x;   // 6,400,000 threads, 8 elems each
  const float4* src = (const float4*)f;
  float4 v0 = src[g * 2], v1 = src[g * 2 + 1];
  f16x8 o;
  o[0] = (_Float16)v0.x; o[1] = (_Float16)v0.y; o[2] = (_Float16)v0.z; o[3] = (_Float16)v0.w;
  o[4] = (_Float16)v1.x; o[5] = (_Float16)v1.y; o[6] = (_Float16)v1.z; o[7] = (_Float16)v1.w;
  ((f16x8*)fh)[g] = o;
}

// ---------------- pack W1/W2/W3 into B-fragment order ----------------
// B frag for mfma_f32_32x32x16_f16: lane holds 8 f16: B[kk][c], c = ct*32+(lane&31),
// kk = ko*16 + (lane>>5)*8 + j. Packed flat: [k][ko][ct][lane][8].
__global__ __launch_bounds__(256) void pack_w(const float* __restrict__ W1,
                                              const float* __restrict__ W2,
                                              const float* __restrict__ W3,
                                              _Float16* __restrict__ pW1,
                                              _Float16* __restrict__ pW2,
                                              _Float16* __restrict__ pW3) {
  int gid = blockIdx.x * 256 + threadIdx.x;            // 112,640 total
  const float* W; _Float16* dst; int k, rem;
  if (gid < 110592) {
    int mat = gid / 55296, r = gid % 55296;
    W = mat ? W2 : W1; dst = (mat ? pW2 : pW1) + (size_t)r * 8;
    k = r >> 11; rem = r & 2047;
  } else {
    int r = gid - 110592;                              // 0..2047
    W = W3; dst = pW3 + (size_t)r * 8; k = 0; rem = r;
  }
  int ko = rem >> 8, ct = (rem >> 6) & 3, lane = rem & 63;
  int h = lane >> 5, c = ct * 32 + (lane & 31);
  f16x8 o;
#pragma unroll
  for (int j = 0; j < 8; ++j) {
    int kk = ko * 16 + h * 8 + j;
    o[j] = (_Float16)W[(size_t)(k * 128 + kk) * 128 + c];
  }
  *(f16x8*)dst = o;
}

// ---------------- conv kernel (pipelined) ----------------
// One conv per block, 256 rows per block, 4 waves x 64 rows (R=2 row-tiles, full 128 cols).
// W double-buffered in LDS (2x32KB), staged with global_load_lds one k ahead.
// Raw s_barrier + counted s_waitcnt vmcnt(28): W(k) was issued a full iteration earlier,
// so its L2 latency is hidden under compute(k-1). Never vmcnt(0) in the main loop.
// Masked/OOB gathers are redirected to a zeroed row (ZOFF) -> unconditional loads.
//
// Per-iteration VMEM issue order per wave (pinned by sched_barrier(0) groups):
//   [a: 16 A-gathers(k)] [b: 4 idx/mask(k+1)] [c: 8 global_load_lds W(k+1)]
// At the wait point: leftover c'(8, = W(k)) + 28 new = 36 outstanding;
// vmcnt(28) drains exactly c'. Compiler's own counted waits handle a/b.
__global__ __launch_bounds__(256, 2) void conv_kernel(
    const _Float16* __restrict__ featsh, const int* __restrict__ nidx,
    const int* __restrict__ nmask, const int* __restrict__ segids,
    const _Float16* __restrict__ pW1, const _Float16* __restrict__ pW2,
    const float* __restrict__ b1, const float* __restrict__ b2,
    _Float16* __restrict__ out1, _Float16* __restrict__ out2,
    float* __restrict__ seg_sums, float* __restrict__ cnts_f) {
  __shared__ __align__(16) char lds_raw[65536];   // W dbuf 2x32KB; epilogue transpose reuse
  int tid = threadIdx.x, w = tid >> 6, lane = tid & 63, h = lane >> 5;
  int bid = blockIdx.x;
  int conv = bid & 1;
  int n0 = (bid >> 1) * 256;
  int row0 = n0 + w * 64 + (lane & 31);
  int row1 = row0 + 32;
  bool v0 = row0 < NPTS, v1 = row1 < NPTS;            // tail block (last 128 rows short)
  int rc0 = v0 ? row0 : 0, rc1 = v1 ? row1 : 0;       // clamped for idx/mask loads

  const char* fb = (const char*)featsh;               // byte base; zero row at ZOFF
  const char* srcW = (const char*)(conv ? pW2 : pW1);

  floatx16 acc0[4], acc1[4];
#pragma unroll
  for (int ct = 0; ct < 4; ++ct)
#pragma unroll
    for (int r = 0; r < 16; ++r) { acc0[ct][r] = 0.f; acc1[ct][r] = 0.f; }

  // ---- prologue: idx/mask(0), stage W(0) into buf0, full drain once ----
  int i0 = nidx[(size_t)rc0 * KNB];
  int i1 = nidx[(size_t)rc1 * KNB];
  int m0 = nmask[(size_t)rc0 * KNB];
  int m1 = nmask[(size_t)rc1 * KNB];
#pragma unroll
  for (int it = 0; it < 8; ++it)
    load_lds16(srcW + w * 8192 + it * 1024 + lane * 16,
               lds_raw + w * 8192 + it * 1024);
  int off0 = (v0 && m0) ? i0 * 256 : ZOFF;
  int off1 = (v1 && m1) ? i1 * 256 : ZOFF;
  __syncthreads();                                    // one full drain, outside the loop

  for (int k = 0; k < KNB; ++k) {
    int kn = (k + 1 < KNB) ? k + 1 : KNB - 1;         // clamp: keep VMEM counts uniform

    // [a] A(k) gathers -> VGPRs (16 x dwordx4, unconditional; masked lanes hit zero row)
    uint4 a0r[8], a1r[8];
#pragma unroll
    for (int ko = 0; ko < 8; ++ko) {
      a0r[ko] = *(const uint4*)(fb + off0 + ko * 32 + h * 16);
      a1r[ko] = *(const uint4*)(fb + off1 + ko * 32 + h * 16);
    }
    __builtin_amdgcn_sched_barrier(0);

    // [b] idx/mask(k+1) prefetch (4 loads)
    int ni0 = nidx[(size_t)rc0 * KNB + kn];
    int ni1 = nidx[(size_t)rc1 * KNB + kn];
    int nm0 = nmask[(size_t)rc0 * KNB + kn];
    int nm1 = nmask[(size_t)rc1 * KNB + kn];
    __builtin_amdgcn_sched_barrier(0);

    // [c] stage W(k+1) into buf[(k+1)&1] (8 global_load_lds per wave, 32KB/block)
    {
      const char* sk = srcW + (size_t)kn * 32768;
      char* db = lds_raw + ((k + 1) & 1) * 32768;
#pragma unroll
      for (int it = 0; it < 8; ++it)
        load_lds16(sk + w * 8192 + it * 1024 + lane * 16,
                   db + w * 8192 + it * 1024);
    }
    __builtin_amdgcn_sched_barrier(0);

    // wait W(k) (issued last iteration, oldest 8 of <=36) -- NOT vmcnt(0)
    asm volatile("s_waitcnt vmcnt(28)" ::: "memory");
    __builtin_amdgcn_s_barrier();
    __builtin_amdgcn_sched_barrier(0);

    // compute k from buf[k&1]; compiler inserts counted waits for a-loads/ds_reads
    const _Float16* ldsW = (const _Float16*)(lds_raw + (k & 1) * 32768);
#pragma unroll
    for (int ko = 0; ko < 8; ++ko) {
      f16x8 a0 = __builtin_bit_cast(f16x8, a0r[ko]);
      f16x8 a1 = __builtin_bit_cast(f16x8, a1r[ko]);
#pragma unroll
      for (int ct = 0; ct < 4; ++ct) {
        f16x8 b = *(const f16x8*)(ldsW + ((ko * 4 + ct) * 64 + lane) * 8);
        acc0[ct] = __builtin_amdgcn_mfma_f32_32x32x16_f16(a0, b, acc0[ct], 0, 0, 0);
        acc1[ct] = __builtin_amdgcn_mfma_f32_32x32x16_f16(a1, b, acc1[ct], 0, 0, 0);
      }
    }
    // next gather addresses (waits [b] via compiler)
    off0 = (v0 && nm0) ? ni0 * 256 : ZOFF;
    off1 = (v1 && nm1) ? ni1 * 256 : ZOFF;
    __builtin_amdgcn_sched_barrier(0);
    __builtin_amdgcn_s_barrier();                     // protect buf being restaged next iter
    __builtin_amdgcn_sched_barrier(0);
  }

  // ---- epilogue: bias + relu ----
  const float* bb = conv ? b2 : b1;
  float bias[4];
#pragma unroll
  for (int ct = 0; ct < 4; ++ct) bias[ct] = bb[ct * 32 + (lane & 31)];
#pragma unroll
  for (int ct = 0; ct < 4; ++ct)
#pragma unroll
    for (int r = 0; r < 16; ++r) {
      acc0[ct][r] = fmaxf(acc0[ct][r] + bias[ct], 0.f);
      acc1[ct][r] = fmaxf(acc1[ct][r] + bias[ct], 0.f);
    }

  int last = n0 + 255 < NPTS ? n0 + 255 : NPTS - 1;
  int seg0 = segids[n0];
  bool uniform = (seg0 == segids[last]);              // segment_ids are sorted
  int nvalid = (NPTS - n0 < 256) ? (NPTS - n0) : 256;

  // segment column sums of out2 (uniform fast path: per-wave shuffle reduce + atomics)
  if (conv == 1 && uniform) {
    if ((n0 + w * 64) < NPTS) {                       // tail waves are all-valid/all-invalid
#pragma unroll
      for (int ct = 0; ct < 4; ++ct) {
        float s = 0.f;
#pragma unroll
        for (int r = 0; r < 16; ++r) s += acc0[ct][r] + acc1[ct][r];
        s += __shfl_xor(s, 32);
        if (lane < 32) atomicAdd(&seg_sums[seg0 * 128 + ct * 32 + lane], s);
      }
    }
    if (tid == 0) atomicAdd(&cnts_f[seg0], (float)nvalid);
  }

  __syncthreads();                                    // drains stale last staging too
  // transpose C-layout accs -> row-major f16 in LDS [256][128]
  _Float16* lds_out = (_Float16*)lds_raw;
#pragma unroll
  for (int ct = 0; ct < 4; ++ct) {
    int col = ct * 32 + (lane & 31);
#pragma unroll
    for (int r = 0; r < 16; ++r) {
      int lr = w * 64 + (r & 3) + 8 * (r >> 2) + 4 * h;   // C/D row mapping (m74/m101)
      lds_out[lr * 128 + col] = (_Float16)acc0[ct][r];
      lds_out[(lr + 32) * 128 + col] = (_Float16)acc1[ct][r];
    }
  }
  __syncthreads();

  if (conv == 1 && !uniform) {                        // rare boundary blocks (<=7)
    if (n0 + tid < NPTS) {
      int s = segids[n0 + tid];
      atomicAdd(&cnts_f[s], 1.0f);
      for (int c = 0; c < 128; ++c)
        atomicAdd(&seg_sums[s * 128 + c], (float)lds_out[tid * 128 + c]);
    }
  }

  // coalesced row-major stores (64KB per block)
  _Float16* outp = conv ? out2 : out1;
#pragma unroll
  for (int it = 0; it < 16; ++it) {
    int chunk = it * 256 + tid;                       // 0..4095, 16B each
    if (n0 + (chunk >> 4) < NPTS) {
      uint4 v = *(const uint4*)(lds_raw + chunk * 16);
      *(uint4*)(outp + (size_t)n0 * 128 + (size_t)chunk * 8) = v;
    }
  }
}

// ---------------- final kernel: enc/mid + mid@W3 + relu(feats - relu(.)) ----------------
__global__ __launch_bounds__(256, 2) void final_kernel(
    const float* __restrict__ feats, const _Float16* __restrict__ out1,
    const _Float16* __restrict__ out2, const int* __restrict__ segids,
    const float* __restrict__ seg_sums, const float* __restrict__ cnts_f,
    const char* __restrict__ pW3, const float* __restrict__ b3,
    float* __restrict__ dout) {
  __shared__ __align__(16) char ldsw3[32768];
  __shared__ float smean[NSEG * 128];
  int tid = threadIdx.x, w = tid >> 6, lane = tid & 63, h = lane >> 5;
  int n0 = blockIdx.x * 128;
#pragma unroll
  for (int it = 0; it < 8; ++it)
    load_lds16(pW3 + w * 8192 + it * 1024 + lane * 16, ldsw3 + w * 8192 + it * 1024);
  for (int i = tid; i < NSEG * 128; i += 256)
    smean[i] = seg_sums[i] / fmaxf(cnts_f[i >> 7], 1.0f);
  __syncthreads();

  int row = n0 + w * 32 + (lane & 31);
  int seg = segids[row];
  const char* p1 = (const char*)(out1 + (size_t)row * 128 + h * 8);
  const char* p2 = (const char*)(out2 + (size_t)row * 128 + h * 8);
  f16x8 o1[8], o2[8];
  float s1 = 0.f;
#pragma unroll
  for (int ko = 0; ko < 8; ++ko) {
    o1[ko] = *(const f16x8*)(p1 + ko * 32);
    o2[ko] = *(const f16x8*)(p2 + ko * 32);
#pragma unroll
    for (int j = 0; j < 8; ++j) s1 += (float)o1[ko][j];
  }
  s1 += __shfl_xor(s1, 32);
  float rm = s1 * (1.0f / 128.0f);             // row mean of out1 (out1 >= 0)

  f16x8 a[8];
#pragma unroll
  for (int ko = 0; ko < 8; ++ko) {
    int colb = ko * 16 + h * 8;
#pragma unroll
    for (int j = 0; j < 8; ++j) {
      float m2 = smean[seg * 128 + colb + j];
      float e = sqrtf(fmaf(rm, m2, 1e-12f));
      a[ko][j] = (_Float16)(e + (float)o1[ko][j] + (float)o2[ko][j]);
    }
  }
  floatx16 acc[4];
#pragma unroll
  for (int ct = 0; ct < 4; ++ct)
#pragma unroll
    for (int r = 0; r < 16; ++r) acc[ct][r] = 0.f;
#pragma unroll
  for (int ko = 0; ko < 8; ++ko)
#pragma unroll
    for (int ct = 0; ct < 4; ++ct) {
      f16x8 b = *(const f16x8*)(ldsw3 + ((ko * 4 + ct) * 64 + lane) * 16);
      acc[ct] = __builtin_amdgcn_mfma_f32_32x32x16_f16(a[ko], b, acc[ct], 0, 0, 0);
    }
#pragma unroll
  for (int ct = 0; ct < 4; ++ct) {
    int col = ct * 32 + (lane & 31);
    float bc = b3[col];
#pragma unroll
    for (int r = 0; r < 16; ++r) {
      int gr = n0 + w * 32 + (r & 3) + 8 * (r >> 2) + 4 * h;
      float v = fmaxf(acc[ct][r] + bc, 0.f);
      float f = feats[(size_t)gr * 128 + col];
      dout[(size_t)gr * 128 + col] = fmaxf(f - v, 0.f);
    }
  }
}

extern "C" void kernel_launch(void* const* d_in, const int* in_sizes, int n_in,
                              void* d_out, int out_size, void* d_ws, size_t ws_size,
                              hipStream_t stream) {
  (void)in_sizes; (void)n_in; (void)out_size; (void)ws_size;
  const float* feats = (const float*)d_in[0];
  const int* nidx   = (const int*)d_in[1];
  const int* nmask  = (const int*)d_in[2];   // bool mask; int32 per harness convention
  const int* segids = (const int*)d_in[3];
  const float* W1 = (const float*)d_in[5];
  const float* b1 = (const float*)d_in[6];
  const float* W2 = (const float*)d_in[7];
  const float* b2 = (const float*)d_in[8];
  const float* W3 = (const float*)d_in[9];
  const float* b3 = (const float*)d_in[10];
  float* dout = (float*)d_out;
  char* ws = (char*)d_ws;

  _Float16* featsh = (_Float16*)(ws + OFF_FEATSH);
  _Float16* out1h  = (_Float16*)(ws + OFF_OUT1);
  _Float16* out2h  = (_Float16*)(ws + OFF_OUT2);
  _Float16* pW1    = (_Float16*)(ws + OFF_PW1);
  _Float16* pW2    = (_Float16*)(ws + OFF_PW2);
  _Float16* pW3    = (_Float16*)(ws + OFF_PW3);
  float* seg_sums  = (float*)(ws + OFF_SEG);
  float* cnts_f    = (float*)(ws + OFF_CNT);

  // zero seg sums + counts + the masked-gather zero row (contiguous)
  hipMemsetAsync(ws + OFF_SEG, 0, 4096 + 32 + 256, stream);
  cvt_feats<<<25000, 256, 0, stream>>>(feats, featsh);
  pack_w<<<440, 256, 0, stream>>>(W1, W2, W3, pW1, pW2, pW3);
  conv_kernel<<<3126, 256, 0, stream>>>(featsh, nidx, nmask, segids, pW1, pW2,
                                        b1, b2, out1h, out2h, seg_sums, cnts_f);
  final_kernel<<<3125, 256, 0, stream>>>(feats, out1h, out2h, segids, seg_sums,
                                         cnts_f, (const char*)pW3, b3, dout);
}

// Round 2
// 1727.777 us; speedup vs baseline: 1.1988x; 1.1988x over previous
//
#include <hip/hip_runtime.h>
#include <stdint.h>

// Problem constants
#define NPTS 400000
#define DIM  128
#define KNB  27
#define NSEG 8

typedef _Float16 f16x8 __attribute__((ext_vector_type(8)));
typedef float floatx16 __attribute__((ext_vector_type(16)));

// Workspace layout (bytes). Total ~309 MB + 288 B.
#define OFF_FEATSH 0UL                    // N*128 f16 = 102,400,000
#define OFF_OUT1   102400000UL            // N*128 f16
#define OFF_OUT2   204800000UL            // N*128 f16
#define OFF_PW1    307200000UL            // 27*128*128 f16 = 884,736
#define OFF_PW2    308084736UL
#define OFF_PW3    308969472UL            // 128*128 f16 = 32,768
#define OFF_SEG    309002240UL            // 8*128 f32 = 4096
#define OFF_CNT    309006336UL            // 8 f32 = 32
#define OFF_ZROW   309006368UL            // 256 B zeroed feature row (masked-gather target)
#define ZOFF       309006368              // byte offset of zero row from featsh base

__device__ __forceinline__ void load_lds16(const void* g, void* l) {
  __builtin_amdgcn_global_load_lds(
      (const __attribute__((address_space(1))) void*)g,
      (__attribute__((address_space(3))) void*)l, 16, 0, 0);
}

// ---------------- feats fp32 -> f16 ----------------
__global__ __launch_bounds__(256) void cvt_feats(const float* __restrict__ f,
                                                 _Float16* __restrict__ fh) {
  size_t g = (size_t)blockIdx.x * 256 + threadIdx.x;   // 6,400,000 threads, 8 elems each
  const float4* src = (const float4*)f;
  float4 v0 = src[g * 2], v1 = src[g * 2 + 1];
  f16x8 o;
  o[0] = (_Float16)v0.x; o[1] = (_Float16)v0.y; o[2] = (_Float16)v0.z; o[3] = (_Float16)v0.w;
  o[4] = (_Float16)v1.x; o[5] = (_Float16)v1.y; o[6] = (_Float16)v1.z; o[7] = (_Float16)v1.w;
  ((f16x8*)fh)[g] = o;
}

// ---------------- pack W1/W2/W3 into B-fragment order ----------------
// B frag for mfma_f32_32x32x16_f16: lane holds 8 f16: B[kk][c], c = ct*32+(lane&31),
// kk = ko*16 + (lane>>5)*8 + j. Packed flat: [k][ko][ct][lane][8].
__global__ __launch_bounds__(256) void pack_w(const float* __restrict__ W1,
                                              const float* __restrict__ W2,
                                              const float* __restrict__ W3,
                                              _Float16* __restrict__ pW1,
                                              _Float16* __restrict__ pW2,
                                              _Float16* __restrict__ pW3) {
  int gid = blockIdx.x * 256 + threadIdx.x;            // 112,640 total
  const float* W; _Float16* dst; int k, rem;
  if (gid < 110592) {
    int mat = gid / 55296, r = gid % 55296;
    W = mat ? W2 : W1; dst = (mat ? pW2 : pW1) + (size_t)r * 8;
    k = r >> 11; rem = r & 2047;
  } else {
    int r = gid - 110592;                              // 0..2047
    W = W3; dst = pW3 + (size_t)r * 8; k = 0; rem = r;
  }
  int ko = rem >> 8, ct = (rem >> 6) & 3, lane = rem & 63;
  int h = lane >> 5, c = ct * 32 + (lane & 31);
  f16x8 o;
#pragma unroll
  for (int j = 0; j < 8; ++j) {
    int kk = ko * 16 + h * 8 + j;
    o[j] = (_Float16)W[(size_t)(k * 128 + kk) * 128 + c];
  }
  *(f16x8*)dst = o;
}

// ---------------- conv kernel (fully pipelined, fused convs) ----------------
// Block = 256 thr (4 waves) = 128 rows, BOTH convs (waves 0,1 -> conv0; 2,3 -> conv1;
// rowgroup g = w&1). Gather sharing between conv waves via L1 (same addresses).
// Three pipelined streams, each one iteration deep:
//   A(k+1) -> register double-buffer (16 uint4 per set),
//   idx/mask(k+2) -> scalar-ish prefetch,
//   W(k+1) -> LDS double buffer (2 x 64KB), counted s_waitcnt vmcnt(36) (never 0).
// 1 wave/SIMD by design (launch_bounds(256,1), ~285 VGPR); latency hidden by the
// 2048-cycle MFMA phase (64 x mfma_32x32x16 @ ~32 cyc), not TLP.
__global__ __launch_bounds__(256, 1) void conv_kernel(
    const _Float16* __restrict__ featsh, const int* __restrict__ nidx,
    const int* __restrict__ nmask, const int* __restrict__ segids,
    const _Float16* __restrict__ pW1, const _Float16* __restrict__ pW2,
    const float* __restrict__ b1, const float* __restrict__ b2,
    _Float16* __restrict__ out1, _Float16* __restrict__ out2,
    float* __restrict__ seg_sums, float* __restrict__ cnts_f) {
  __shared__ __align__(16) char lds_raw[131072];       // W dbuf 2x64KB; epilogue reuse
  int tid = threadIdx.x, w = tid >> 6, lane = tid & 63, h = lane >> 5;
  int conv = w >> 1, g = w & 1;
  int n0 = blockIdx.x * 128;                           // 3125*128 = 400,000 exact, no tail
  int row0 = n0 + g * 64 + (lane & 31);
  int row1 = row0 + 32;

  const char* fb = (const char*)featsh;                // zero row at byte ZOFF
  const char* srcW = (const char*)(w < 2 ? pW1 : pW2) + (w & 1) * 16384;

  floatx16 acc0[4], acc1[4];
#pragma unroll
  for (int ct = 0; ct < 4; ++ct)
#pragma unroll
    for (int r = 0; r < 16; ++r) { acc0[ct][r] = 0.f; acc1[ct][r] = 0.f; }

  uint4 aE[16], aO[16];
  int i_n0, i_n1, m_n0, m_n1;

  // ---- prologue: idx(0), idx(1), A(0)->aE, W(0)->buf0 ----
  {
    int i00 = nidx[(size_t)row0 * KNB];
    int i01 = nidx[(size_t)row1 * KNB];
    int m00 = nmask[(size_t)row0 * KNB];
    int m01 = nmask[(size_t)row1 * KNB];
    i_n0 = nidx[(size_t)row0 * KNB + 1];
    i_n1 = nidx[(size_t)row1 * KNB + 1];
    m_n0 = nmask[(size_t)row0 * KNB + 1];
    m_n1 = nmask[(size_t)row1 * KNB + 1];
    int off0 = m00 ? i00 * 256 : ZOFF;
    int off1 = m01 ? i01 * 256 : ZOFF;
#pragma unroll
    for (int ko = 0; ko < 8; ++ko) {
      aE[ko]     = *(const uint4*)(fb + off0 + ko * 32 + h * 16);
      aE[ko + 8] = *(const uint4*)(fb + off1 + ko * 32 + h * 16);
    }
#pragma unroll
    for (int it = 0; it < 16; ++it)
      load_lds16(srcW + it * 1024 + lane * 16, lds_raw + w * 16384 + it * 1024);
  }

  // Per-iteration VMEM per wave: A:16, idx:4, W-stage:16.  At the wait point the ops
  // younger than the last W(k) stage are exactly A(k+1)16 + idx(k+2)4 + W(k+1)16 = 36.
#define CONV_STEP(ACUR, ANXT, K)                                                   \
  {                                                                                \
    const int k_ = (K);                                                            \
    int offn0 = m_n0 ? i_n0 * 256 : ZOFF;            /* waits idx(k+1) only */     \
    int offn1 = m_n1 ? i_n1 * 256 : ZOFF;                                          \
    __builtin_amdgcn_sched_barrier(0);                                             \
    _Pragma("unroll")                                                              \
    for (int ko = 0; ko < 8; ++ko) {                 /* A(k+1) gathers */          \
      ANXT[ko]     = *(const uint4*)(fb + offn0 + ko * 32 + h * 16);               \
      ANXT[ko + 8] = *(const uint4*)(fb + offn1 + ko * 32 + h * 16);               \
    }                                                                              \
    __builtin_amdgcn_sched_barrier(0);                                             \
    {                                                /* idx/mask(k+2) */           \
      int kq = (k_ + 2 <= KNB - 1) ? k_ + 2 : KNB - 1;                             \
      i_n0 = nidx[(size_t)row0 * KNB + kq];                                        \
      i_n1 = nidx[(size_t)row1 * KNB + kq];                                        \
      m_n0 = nmask[(size_t)row0 * KNB + kq];                                       \
      m_n1 = nmask[(size_t)row1 * KNB + kq];                                       \
    }                                                                              \
    __builtin_amdgcn_sched_barrier(0);                                             \
    {                                                /* W(k+1) -> buf[(k+1)&1] */  \
      int ks = (k_ + 1 <= KNB - 1) ? k_ + 1 : KNB - 1;                             \
      const char* sk = srcW + (size_t)ks * 32768;                                  \
      char* db = lds_raw + ((k_ + 1) & 1) * 65536 + w * 16384;                     \
      _Pragma("unroll")                                                            \
      for (int it = 0; it < 16; ++it)                                              \
        load_lds16(sk + it * 1024 + lane * 16, db + it * 1024);                    \
    }                                                                              \
    __builtin_amdgcn_sched_barrier(0);                                             \
    asm volatile("s_waitcnt vmcnt(36)" ::: "memory"); /* drain W(k), keep rest */  \
    __builtin_amdgcn_s_barrier();                                                  \
    __builtin_amdgcn_sched_barrier(0);                                             \
    const _Float16* ldsW =                                                         \
        (const _Float16*)(lds_raw + (k_ & 1) * 65536 + conv * 32768);              \
    _Pragma("unroll")                                                              \
    for (int ko = 0; ko < 8; ++ko) {                                               \
      f16x8 a0 = __builtin_bit_cast(f16x8, ACUR[ko]);                              \
      f16x8 a1 = __builtin_bit_cast(f16x8, ACUR[ko + 8]);                          \
      _Pragma("unroll")                                                            \
      for (int ct = 0; ct < 4; ++ct) {                                             \
        f16x8 b = *(const f16x8*)(ldsW + ((ko * 4 + ct) * 64 + lane) * 8);         \
        acc0[ct] = __builtin_amdgcn_mfma_f32_32x32x16_f16(a0, b, acc0[ct], 0, 0, 0); \
        acc1[ct] = __builtin_amdgcn_mfma_f32_32x32x16_f16(a1, b, acc1[ct], 0, 0, 0); \
      }                                                                            \
    }                                                                              \
    __builtin_amdgcn_sched_barrier(0);                                             \
    __builtin_amdgcn_s_barrier();                     /* protect buf restaged next */ \
    __builtin_amdgcn_sched_barrier(0);                                             \
  }

  for (int p = 0; p < 13; ++p) {                      // k = 0..25
    CONV_STEP(aE, aO, 2 * p);
    CONV_STEP(aO, aE, 2 * p + 1);
  }
  CONV_STEP(aE, aO, 26);                              // k = 26 (prefetches are clamped)
#undef CONV_STEP

  // ---- epilogue: bias + relu ----
  const float* bb = conv ? b2 : b1;
  float bias[4];
#pragma unroll
  for (int ct = 0; ct < 4; ++ct) bias[ct] = bb[ct * 32 + (lane & 31)];
#pragma unroll
  for (int ct = 0; ct < 4; ++ct)
#pragma unroll
    for (int r = 0; r < 16; ++r) {
      acc0[ct][r] = fmaxf(acc0[ct][r] + bias[ct], 0.f);
      acc1[ct][r] = fmaxf(acc1[ct][r] + bias[ct], 0.f);
    }

  int seg0 = segids[n0];
  bool uniform = (seg0 == segids[n0 + 127]);   // segment_ids are sorted

  // segment column sums of out2 (uniform fast path: per-wave shuffle reduce + atomics)
  if (conv == 1 && uniform) {
#pragma unroll
    for (int ct = 0; ct < 4; ++ct) {
      float s = 0.f;
#pragma unroll
      for (int r = 0; r < 16; ++r) s += acc0[ct][r] + acc1[ct][r];
      s += __shfl_xor(s, 32);
      if (lane < 32) atomicAdd(&seg_sums[seg0 * 128 + ct * 32 + lane], s);
    }
  }
  if (tid == 0 && uniform) atomicAdd(&cnts_f[seg0], 128.0f);

  __syncthreads();                             // full drain (incl. stray clamped stages)
  // transpose C-layout accs -> row-major f16 in LDS [2][128][128]
  _Float16* lds_out = (_Float16*)lds_raw;
#pragma unroll
  for (int ct = 0; ct < 4; ++ct) {
    int col = ct * 32 + (lane & 31);
#pragma unroll
    for (int r = 0; r < 16; ++r) {
      int lr = g * 64 + (r & 3) + 8 * (r >> 2) + 4 * h;   // C/D row mapping (m74/m101)
      lds_out[conv * 16384 + lr * 128 + col] = (_Float16)acc0[ct][r];
      lds_out[conv * 16384 + (lr + 32) * 128 + col] = (_Float16)acc1[ct][r];
    }
  }
  __syncthreads();

  if (!uniform && tid < 128) {                 // rare boundary blocks: per-row atomics
    int s = segids[n0 + tid];
    atomicAdd(&cnts_f[s], 1.0f);
    for (int c = 0; c < 128; ++c)
      atomicAdd(&seg_sums[s * 128 + c], (float)lds_out[16384 + tid * 128 + c]);
  }

  // coalesced row-major stores of out1/out2 (64KB total)
#pragma unroll
  for (int it = 0; it < 16; ++it) {
    int chunk = it * 256 + tid;                // 0..4095, 16B each
    int cv = chunk >> 11;
    int off16 = chunk & 2047;
    uint4 v = *(const uint4*)(lds_raw + cv * 32768 + off16 * 16);
    *(uint4*)((cv ? out2 : out1) + (size_t)n0 * 128 + off16 * 8) = v;
  }
}

// ---------------- final kernel: enc/mid + mid@W3 + relu(feats - relu(.)) ----------------
__global__ __launch_bounds__(256, 2) void final_kernel(
    const float* __restrict__ feats, const _Float16* __restrict__ out1,
    const _Float16* __restrict__ out2, const int* __restrict__ segids,
    const float* __restrict__ seg_sums, const float* __restrict__ cnts_f,
    const char* __restrict__ pW3, const float* __restrict__ b3,
    float* __restrict__ dout) {
  __shared__ __align__(16) char ldsw3[32768];
  __shared__ float smean[NSEG * 128];
  int tid = threadIdx.x, w = tid >> 6, lane = tid & 63, h = lane >> 5;
  int n0 = blockIdx.x * 128;
#pragma unroll
  for (int it = 0; it < 8; ++it)
    load_lds16(pW3 + w * 8192 + it * 1024 + lane * 16, ldsw3 + w * 8192 + it * 1024);
  for (int i = tid; i < NSEG * 128; i += 256)
    smean[i] = seg_sums[i] / fmaxf(cnts_f[i >> 7], 1.0f);
  __syncthreads();

  int row = n0 + w * 32 + (lane & 31);
  int seg = segids[row];
  const char* p1 = (const char*)(out1 + (size_t)row * 128 + h * 8);
  const char* p2 = (const char*)(out2 + (size_t)row * 128 + h * 8);
  f16x8 o1[8], o2[8];
  float s1 = 0.f;
#pragma unroll
  for (int ko = 0; ko < 8; ++ko) {
    o1[ko] = *(const f16x8*)(p1 + ko * 32);
    o2[ko] = *(const f16x8*)(p2 + ko * 32);
#pragma unroll
    for (int j = 0; j < 8; ++j) s1 += (float)o1[ko][j];
  }
  s1 += __shfl_xor(s1, 32);
  float rm = s1 * (1.0f / 128.0f);             // row mean of out1 (out1 >= 0)

  f16x8 a[8];
#pragma unroll
  for (int ko = 0; ko < 8; ++ko) {
    int colb = ko * 16 + h * 8;
#pragma unroll
    for (int j = 0; j < 8; ++j) {
      float m2 = smean[seg * 128 + colb + j];
      float e = sqrtf(fmaf(rm, m2, 1e-12f));
      a[ko][j] = (_Float16)(e + (float)o1[ko][j] + (float)o2[ko][j]);
    }
  }
  floatx16 acc[4];
#pragma unroll
  for (int ct = 0; ct < 4; ++ct)
#pragma unroll
    for (int r = 0; r < 16; ++r) acc[ct][r] = 0.f;
#pragma unroll
  for (int ko = 0; ko < 8; ++ko)
#pragma unroll
    for (int ct = 0; ct < 4; ++ct) {
      f16x8 b = *(const f16x8*)(ldsw3 + ((ko * 4 + ct) * 64 + lane) * 16);
      acc[ct] = __builtin_amdgcn_mfma_f32_32x32x16_f16(a[ko], b, acc[ct], 0, 0, 0);
    }
#pragma unroll
  for (int ct = 0; ct < 4; ++ct) {
    int col = ct * 32 + (lane & 31);
    float bc = b3[col];
#pragma unroll
    for (int r = 0; r < 16; ++r) {
      int gr = n0 + w * 32 + (r & 3) + 8 * (r >> 2) + 4 * h;
      float v = fmaxf(acc[ct][r] + bc, 0.f);
      float f = feats[(size_t)gr * 128 + col];
      dout[(size_t)gr * 128 + col] = fmaxf(f - v, 0.f);
    }
  }
}

extern "C" void kernel_launch(void* const* d_in, const int* in_sizes, int n_in,
                              void* d_out, int out_size, void* d_ws, size_t ws_size,
                              hipStream_t stream) {
  (void)in_sizes; (void)n_in; (void)out_size; (void)ws_size;
  const float* feats = (const float*)d_in[0];
  const int* nidx   = (const int*)d_in[1];
  const int* nmask  = (const int*)d_in[2];   // bool mask; int32 per harness convention
  const int* segids = (const int*)d_in[3];
  const float* W1 = (const float*)d_in[5];
  const float* b1 = (const float*)d_in[6];
  const float* W2 = (const float*)d_in[7];
  const float* b2 = (const float*)d_in[8];
  const float* W3 = (const float*)d_in[9];
  const float* b3 = (const float*)d_in[10];
  float* dout = (float*)d_out;
  char* ws = (char*)d_ws;

  _Float16* featsh = (_Float16*)(ws + OFF_FEATSH);
  _Float16* out1h  = (_Float16*)(ws + OFF_OUT1);
  _Float16* out2h  = (_Float16*)(ws + OFF_OUT2);
  _Float16* pW1    = (_Float16*)(ws + OFF_PW1);
  _Float16* pW2    = (_Float16*)(ws + OFF_PW2);
  _Float16* pW3    = (_Float16*)(ws + OFF_PW3);
  float* seg_sums  = (float*)(ws + OFF_SEG);
  float* cnts_f    = (float*)(ws + OFF_CNT);

  // zero seg sums + counts + the masked-gather zero row (contiguous)
  hipMemsetAsync(ws + OFF_SEG, 0, 4096 + 32 + 256, stream);
  cvt_feats<<<25000, 256, 0, stream>>>(feats, featsh);
  pack_w<<<440, 256, 0, stream>>>(W1, W2, W3, pW1, pW2, pW3);
  conv_kernel<<<3125, 256, 0, stream>>>(featsh, nidx, nmask, segids, pW1, pW2,
                                        b1, b2, out1h, out2h, seg_sums, cnts_f);
  final_kernel<<<3125, 256, 0, stream>>>(feats, out1h, out2h, segids, seg_sums,
                                         cnts_f, (const char*)pW3, b3, dout);
}

// Round 3
// 1570.406 us; speedup vs baseline: 1.3190x; 1.1002x over previous
//
#include <hip/hip_runtime.h>
#include <stdint.h>

// Problem constants
#define NPTS 400000
#define DIM  128
#define KNB  27
#define NSEG 8

typedef _Float16 f16x8 __attribute__((ext_vector_type(8)));
typedef float floatx16 __attribute__((ext_vector_type(16)));

// Workspace layout (bytes). Total ~309 MB + 288 B.
#define OFF_FEATSH 0UL                    // N*128 f16 = 102,400,000
#define OFF_OUT1   102400000UL            // N*128 f16
#define OFF_OUT2   204800000UL            // N*128 f16
#define OFF_PW1    307200000UL            // 27*128*128 f16 = 884,736
#define OFF_PW2    308084736UL
#define OFF_PW3    308969472UL            // 128*128 f16 = 32,768
#define OFF_SEG    309002240UL            // 8*128 f32 = 4096
#define OFF_CNT    309006336UL            // 8 f32 = 32
#define OFF_ZROW   309006368UL            // 256 B zeroed feature row (masked-gather target)
#define ZOFF       309006368              // byte offset of zero row from featsh base

#define LDS_A_OFF  131072                 // A staging buffer (32KB) after W dbuf (2x64KB)

__device__ __forceinline__ void load_lds16(const void* g, void* l) {
  __builtin_amdgcn_global_load_lds(
      (const __attribute__((address_space(1))) void*)g,
      (__attribute__((address_space(3))) void*)l, 16, 0, 0);
}

// ---------------- feats fp32 -> f16 ----------------
__global__ __launch_bounds__(256) void cvt_feats(const float* __restrict__ f,
                                                 _Float16* __restrict__ fh) {
  size_t g = (size_t)blockIdx.x * 256 + threadIdx.x;   // 6,400,000 threads, 8 elems each
  const float4* src = (const float4*)f;
  float4 v0 = src[g * 2], v1 = src[g * 2 + 1];
  f16x8 o;
  o[0] = (_Float16)v0.x; o[1] = (_Float16)v0.y; o[2] = (_Float16)v0.z; o[3] = (_Float16)v0.w;
  o[4] = (_Float16)v1.x; o[5] = (_Float16)v1.y; o[6] = (_Float16)v1.z; o[7] = (_Float16)v1.w;
  ((f16x8*)fh)[g] = o;
}

// ---------------- pack W1/W2/W3 into B-fragment order ----------------
// B frag for mfma_f32_32x32x16_f16: lane holds 8 f16: B[kk][c], c = ct*32+(lane&31),
// kk = ko*16 + (lane>>5)*8 + j. Packed flat: [k][ko][ct][lane][8].
__global__ __launch_bounds__(256) void pack_w(const float* __restrict__ W1,
                                              const float* __restrict__ W2,
                                              const float* __restrict__ W3,
                                              _Float16* __restrict__ pW1,
                                              _Float16* __restrict__ pW2,
                                              _Float16* __restrict__ pW3) {
  int gid = blockIdx.x * 256 + threadIdx.x;            // 112,640 total
  const float* W; _Float16* dst; int k, rem;
  if (gid < 110592) {
    int mat = gid / 55296, r = gid % 55296;
    W = mat ? W2 : W1; dst = (mat ? pW2 : pW1) + (size_t)r * 8;
    k = r >> 11; rem = r & 2047;
  } else {
    int r = gid - 110592;                              // 0..2047
    W = W3; dst = pW3 + (size_t)r * 8; k = 0; rem = r;
  }
  int ko = rem >> 8, ct = (rem >> 6) & 3, lane = rem & 63;
  int h = lane >> 5, c = ct * 32 + (lane & 31);
  f16x8 o;
#pragma unroll
  for (int j = 0; j < 8; ++j) {
    int kk = ko * 16 + h * 8 + j;
    o[j] = (_Float16)W[(size_t)(k * 128 + kk) * 128 + c];
  }
  *(f16x8*)dst = o;
}

// ---------------- conv kernel: LDS-staged A shared by both convs ----------------
// Block = 512 thr (8 waves) = 128 rows, both convs. Wave ws: conv = ws>>2,
// rowgroup g2 = ws&3 (32 rows, one acc set of 4 -> 64 VGPR).
// Key change vs R2: A rows gathered ONCE per block (not once per conv) with
// row-coalesced lanes (4 lanes x 16B = full 64B line per row per instr), staged to a
// chunked LDS_A layout [chunk=byte>>4][row][16B] so MFMA A-frag ds_reads are the
// canonical contiguous conflict-free pattern. Line-requests/CU-iter drop ~3600->~1750.
// Pipeline (T3/T4/T14): W dbuf 2x64KB global_load_lds one k ahead, counted vmcnt(14)
// (never 0); A(k+1) gathered to regs at top of iter k, ds_written AFTER the
// post-compute barrier; idx(k+2) two iters ahead. 2 barriers/iter.
__global__ __launch_bounds__(512, 2) void conv_kernel(
    const _Float16* __restrict__ featsh, const int* __restrict__ nidx,
    const int* __restrict__ nmask, const int* __restrict__ segids,
    const _Float16* __restrict__ pW1, const _Float16* __restrict__ pW2,
    const float* __restrict__ b1, const float* __restrict__ b2,
    _Float16* __restrict__ out1, _Float16* __restrict__ out2,
    float* __restrict__ seg_sums, float* __restrict__ cnts_f) {
  __shared__ __align__(16) char lds_raw[163840];  // [0,128K): W dbuf; [128K,160K): A
  int tid = threadIdx.x, ws = tid >> 6, lane = tid & 63, h = lane >> 5;
  int conv = ws >> 2, g2 = ws & 3;
  int n0 = blockIdx.x * 128;                      // 3125*128 = 400,000 exact
  int srow = ws * 16 + (lane >> 2);               // staging row 0..127 (4 lanes/row)
  int jlane = lane & 3;                           // 16B sub-chunk within 64B
  size_t gidx = (size_t)(n0 + srow) * KNB;        // nidx/nmask base for staging row

  const char* fb = (const char*)featsh;           // zero row at byte ZOFF
  const char* srcW = (const char*)(ws < 4 ? pW1 : pW2) + (size_t)(ws & 3) * 8192;

  floatx16 acc[4];
#pragma unroll
  for (int ct = 0; ct < 4; ++ct)
#pragma unroll
    for (int r = 0; r < 16; ++r) acc[ct][r] = 0.f;

  // ---- prologue: idx(0), idx(1), gather A(0)->regs, W(0)->buf0, A(0)->LDS ----
  int i_nxt, m_nxt;
  {
    int i0 = nidx[gidx + 0];
    int m0 = nmask[gidx + 0];
    i_nxt = nidx[gidx + 1];
    m_nxt = nmask[gidx + 1];
    int off = m0 ? i0 * 256 : ZOFF;
    uint4 ag[4];
#pragma unroll
    for (int j = 0; j < 4; ++j)
      ag[j] = *(const uint4*)(fb + off + j * 64 + jlane * 16);
#pragma unroll
    for (int it = 0; it < 8; ++it)
      load_lds16(srcW + it * 1024 + lane * 16, lds_raw + ws * 8192 + it * 1024);
    // ds_write A(0): compiler inserts the vmcnt wait for ag
#pragma unroll
    for (int j = 0; j < 4; ++j)
      *(uint4*)(lds_raw + LDS_A_OFF + (size_t)(j * 4 + jlane) * 2048 + srow * 16) = ag[j];
    asm volatile("s_waitcnt lgkmcnt(0)" ::: "memory");
  }

  // Per-iter VMEM per wave: g4 + i2 + w8 = 14.  Entering iter k the only
  // outstanding older ops are W(k) (8) [+ idx(k+1) (2), drained by the compiler's
  // use-wait at the off computation]. vmcnt(14) after issuing 14 drains exactly W(k).
  for (int k = 0; k < KNB; ++k) {
    // [a] gather A(k+1) -> regs (needs idx(k+1): compiler inserts counted wait)
    int off = m_nxt ? i_nxt * 256 : ZOFF;
    uint4 ag[4];
#pragma unroll
    for (int j = 0; j < 4; ++j)
      ag[j] = *(const uint4*)(fb + off + j * 64 + jlane * 16);
    __builtin_amdgcn_sched_barrier(0);
    // [b] idx/mask(k+2) (4-lane dedup -> coalesced)
    {
      int kq = (k + 2 <= KNB - 1) ? k + 2 : KNB - 1;
      i_nxt = nidx[gidx + kq];
      m_nxt = nmask[gidx + kq];
    }
    __builtin_amdgcn_sched_barrier(0);
    // [c] stage W(k+1) -> buf[(k+1)&1]
    {
      int ks = (k + 1 <= KNB - 1) ? k + 1 : KNB - 1;
      const char* sk = srcW + (size_t)ks * 32768;
      char* db = lds_raw + ((k + 1) & 1) * 65536 + ws * 8192;
#pragma unroll
      for (int it = 0; it < 8; ++it)
        load_lds16(sk + it * 1024 + lane * 16, db + it * 1024);
    }
    __builtin_amdgcn_sched_barrier(0);
    asm volatile("s_waitcnt vmcnt(14)" ::: "memory");  // drain W(k); keep the rest
    __builtin_amdgcn_s_barrier();                      // BARRIER1: A(k)/W(k) ready
    __builtin_amdgcn_sched_barrier(0);

    // compute(k): A-frags from LDS_A (contiguous, conflict-free), B from W-buf
    const char* ldsA = lds_raw + LDS_A_OFF;
    const _Float16* ldsW =
        (const _Float16*)(lds_raw + (k & 1) * 65536 + conv * 32768);
#pragma unroll
    for (int ko = 0; ko < 8; ++ko) {
      f16x8 a = *(const f16x8*)(ldsA + (size_t)(ko * 2 + h) * 2048 +
                                (g2 * 32 + (lane & 31)) * 16);
#pragma unroll
      for (int ct = 0; ct < 4; ++ct) {
        f16x8 b = *(const f16x8*)(ldsW + ((ko * 4 + ct) * 64 + lane) * 8);
        acc[ct] = __builtin_amdgcn_mfma_f32_32x32x16_f16(a, b, acc[ct], 0, 0, 0);
      }
    }
    __builtin_amdgcn_sched_barrier(0);
    __builtin_amdgcn_s_barrier();                      // BARRIER2: done reading A(k)
    __builtin_amdgcn_sched_barrier(0);
    // ds_write A(k+1) (compiler waits the g4 gathers; W/idx stay in flight)
#pragma unroll
    for (int j = 0; j < 4; ++j)
      *(uint4*)(lds_raw + LDS_A_OFF + (size_t)(j * 4 + jlane) * 2048 + srow * 16) = ag[j];
    asm volatile("s_waitcnt lgkmcnt(0)" ::: "memory");
    __builtin_amdgcn_sched_barrier(0);
  }

  // ---- epilogue: bias + relu ----
  const float* bb = conv ? b2 : b1;
  float bias[4];
#pragma unroll
  for (int ct = 0; ct < 4; ++ct) bias[ct] = bb[ct * 32 + (lane & 31)];
#pragma unroll
  for (int ct = 0; ct < 4; ++ct)
#pragma unroll
    for (int r = 0; r < 16; ++r)
      acc[ct][r] = fmaxf(acc[ct][r] + bias[ct], 0.f);

  int seg0 = segids[n0];
  bool uniform = (seg0 == segids[n0 + 127]);   // segment_ids are sorted

  // segment column sums of out2 (uniform fast path: per-wave shuffle reduce + atomics)
  if (conv == 1 && uniform) {
#pragma unroll
    for (int ct = 0; ct < 4; ++ct) {
      float s = 0.f;
#pragma unroll
      for (int r = 0; r < 16; ++r) s += acc[ct][r];
      s += __shfl_xor(s, 32);
      if (lane < 32) atomicAdd(&seg_sums[seg0 * 128 + ct * 32 + lane], s);
    }
  }
  if (tid == 0 && uniform) atomicAdd(&cnts_f[seg0], 128.0f);

  __syncthreads();                             // full drain (incl. stray clamped stages)
  // transpose C-layout accs -> row-major f16 in LDS [2][128][128] (reuses W buf0/1 area)
  _Float16* lds_out = (_Float16*)lds_raw;
#pragma unroll
  for (int ct = 0; ct < 4; ++ct) {
    int col = ct * 32 + (lane & 31);
#pragma unroll
    for (int r = 0; r < 16; ++r) {
      int lr = g2 * 32 + (r & 3) + 8 * (r >> 2) + 4 * h;   // C/D row mapping (m74/m101)
      lds_out[conv * 16384 + lr * 128 + col] = (_Float16)acc[ct][r];
    }
  }
  __syncthreads();

  if (!uniform && tid < 128) {                 // rare boundary blocks: per-row atomics
    int s = segids[n0 + tid];
    atomicAdd(&cnts_f[s], 1.0f);
    for (int c = 0; c < 128; ++c)
      atomicAdd(&seg_sums[s * 128 + c], (float)lds_out[16384 + tid * 128 + c]);
  }

  // coalesced row-major stores of out1/out2 (64KB total)
#pragma unroll
  for (int it = 0; it < 8; ++it) {
    int chunk = it * 512 + tid;                // 0..4095, 16B each
    int cv = chunk >> 11;
    int off16 = chunk & 2047;
    uint4 v = *(const uint4*)(lds_raw + cv * 32768 + off16 * 16);
    *(uint4*)((cv ? out2 : out1) + (size_t)n0 * 128 + off16 * 8) = v;
  }
}

// ---------------- final kernel: enc/mid + mid@W3 + relu(feats - relu(.)) ----------------
__global__ __launch_bounds__(256, 2) void final_kernel(
    const float* __restrict__ feats, const _Float16* __restrict__ out1,
    const _Float16* __restrict__ out2, const int* __restrict__ segids,
    const float* __restrict__ seg_sums, const float* __restrict__ cnts_f,
    const char* __restrict__ pW3, const float* __restrict__ b3,
    float* __restrict__ dout) {
  __shared__ __align__(16) char ldsw3[32768];
  __shared__ float smean[NSEG * 128];
  int tid = threadIdx.x, w = tid >> 6, lane = tid & 63, h = lane >> 5;
  int n0 = blockIdx.x * 128;
#pragma unroll
  for (int it = 0; it < 8; ++it)
    load_lds16(pW3 + w * 8192 + it * 1024 + lane * 16, ldsw3 + w * 8192 + it * 1024);
  for (int i = tid; i < NSEG * 128; i += 256)
    smean[i] = seg_sums[i] / fmaxf(cnts_f[i >> 7], 1.0f);
  __syncthreads();

  int row = n0 + w * 32 + (lane & 31);
  int seg = segids[row];
  const char* p1 = (const char*)(out1 + (size_t)row * 128 + h * 8);
  const char* p2 = (const char*)(out2 + (size_t)row * 128 + h * 8);
  f16x8 o1[8], o2[8];
  float s1 = 0.f;
#pragma unroll
  for (int ko = 0; ko < 8; ++ko) {
    o1[ko] = *(const f16x8*)(p1 + ko * 32);
    o2[ko] = *(const f16x8*)(p2 + ko * 32);
#pragma unroll
    for (int j = 0; j < 8; ++j) s1 += (float)o1[ko][j];
  }
  s1 += __shfl_xor(s1, 32);
  float rm = s1 * (1.0f / 128.0f);             // row mean of out1 (out1 >= 0)

  f16x8 a[8];
#pragma unroll
  for (int ko = 0; ko < 8; ++ko) {
    int colb = ko * 16 + h * 8;
#pragma unroll
    for (int j = 0; j < 8; ++j) {
      float m2 = smean[seg * 128 + colb + j];
      float e = sqrtf(fmaf(rm, m2, 1e-12f));
      a[ko][j] = (_Float16)(e + (float)o1[ko][j] + (float)o2[ko][j]);
    }
  }
  floatx16 acc[4];
#pragma unroll
  for (int ct = 0; ct < 4; ++ct)
#pragma unroll
    for (int r = 0; r < 16; ++r) acc[ct][r] = 0.f;
#pragma unroll
  for (int ko = 0; ko < 8; ++ko)
#pragma unroll
    for (int ct = 0; ct < 4; ++ct) {
      f16x8 b = *(const f16x8*)(ldsw3 + ((ko * 4 + ct) * 64 + lane) * 16);
      acc[ct] = __builtin_amdgcn_mfma_f32_32x32x16_f16(a[ko], b, acc[ct], 0, 0, 0);
    }
#pragma unroll
  for (int ct = 0; ct < 4; ++ct) {
    int col = ct * 32 + (lane & 31);
    float bc = b3[col];
#pragma unroll
    for (int r = 0; r < 16; ++r) {
      int gr = n0 + w * 32 + (r & 3) + 8 * (r >> 2) + 4 * h;
      float v = fmaxf(acc[ct][r] + bc, 0.f);
      float f = feats[(size_t)gr * 128 + col];
      dout[(size_t)gr * 128 + col] = fmaxf(f - v, 0.f);
    }
  }
}

extern "C" void kernel_launch(void* const* d_in, const int* in_sizes, int n_in,
                              void* d_out, int out_size, void* d_ws, size_t ws_size,
                              hipStream_t stream) {
  (void)in_sizes; (void)n_in; (void)out_size; (void)ws_size;
  const float* feats = (const float*)d_in[0];
  const int* nidx   = (const int*)d_in[1];
  const int* nmask  = (const int*)d_in[2];   // bool mask; int32 per harness convention
  const int* segids = (const int*)d_in[3];
  const float* W1 = (const float*)d_in[5];
  const float* b1 = (const float*)d_in[6];
  const float* W2 = (const float*)d_in[7];
  const float* b2 = (const float*)d_in[8];
  const float* W3 = (const float*)d_in[9];
  const float* b3 = (const float*)d_in[10];
  float* dout = (float*)d_out;
  char* ws = (char*)d_ws;

  _Float16* featsh = (_Float16*)(ws + OFF_FEATSH);
  _Float16* out1h  = (_Float16*)(ws + OFF_OUT1);
  _Float16* out2h  = (_Float16*)(ws + OFF_OUT2);
  _Float16* pW1    = (_Float16*)(ws + OFF_PW1);
  _Float16* pW2    = (_Float16*)(ws + OFF_PW2);
  _Float16* pW3    = (_Float16*)(ws + OFF_PW3);
  float* seg_sums  = (float*)(ws + OFF_SEG);
  float* cnts_f    = (float*)(ws + OFF_CNT);

  // zero seg sums + counts + the masked-gather zero row (contiguous)
  hipMemsetAsync(ws + OFF_SEG, 0, 4096 + 32 + 256, stream);
  cvt_feats<<<25000, 256, 0, stream>>>(feats, featsh);
  pack_w<<<440, 256, 0, stream>>>(W1, W2, W3, pW1, pW2, pW3);
  conv_kernel<<<3125, 512, 0, stream>>>(featsh, nidx, nmask, segids, pW1, pW2,
                                        b1, b2, out1h, out2h, seg_sums, cnts_f);
  final_kernel<<<3125, 256, 0, stream>>>(feats, out1h, out2h, segids, seg_sums,
                                         cnts_f, (const char*)pW3, b3, dout);
}